// Round 14
// baseline (452.774 us; speedup 1.0000x reference)
//
#include <hip/hip_runtime.h>
#include <hip/hip_bf16.h>

// Problem dims
#define BD   8
#define CD   64      // conv channels / COUT
#define HD   64
#define WD   64
#define LD   4096    // H*W
#define DINN 128
#define KDIR 4
#define NST  16      // d_state
#define L2E  1.442695040888963f

typedef const float* fp;

__device__ __forceinline__ float sigm(float x) { return 1.f / (1.f + __expf(-x)); }
__device__ __forceinline__ float softplusf(float x) {
    float e = __expf(-fabsf(x));
    return fmaxf(x, 0.f) + __logf(1.f + e);
}
// scan position l -> pixel index, for direction k (read pixel == write pixel for all k)
__device__ __forceinline__ int pmap(int k, int l) {
    int m = (k & 2) ? (LD - 1 - l) : l;
    return (k & 1) ? (((m & 63) << 6) | (m >> 6)) : m;
}

// ---------------- weight transpose: cw [co][ci][3][3] -> wt [ci][q][co] ----------------
__global__ __launch_bounds__(256) void k_wt(fp cw, float* wt) {
    int id = blockIdx.x * 256 + threadIdx.x;
    if (id >= 64 * 64 * 9) return;
    int co = id & 63; int ciq = id >> 6; int ci = ciq / 9; int q = ciq % 9;
    wt[id] = cw[(co * 64 + ci) * 9 + q];
}

// ---------------- conv3x3 partial over 32 ci -> conv_out0/1 (B,64,H,W) f32 ----------------
__global__ __launch_bounds__(256, 4) void k_conv(fp x, const float* wt, fp cb,
                                                 float* out0, float* out1) {
    __shared__ float xt[32][3][68];   // [ci][row][w+1], padded
    int bx = blockIdx.x;
    int half = bx & 1; int bh = bx >> 1; int h = bh & 63; int b = bh >> 6;
    int t = threadIdx.x;
    int ci0 = half << 5;
#pragma unroll
    for (int r = 0; r < 3; r++) {
        int hs = h + r - 1;
        bool ok = (hs >= 0 && hs < 64);
        const float* xrow = x + (((size_t)b * 64 + ci0) * 64 + (ok ? hs : 0)) * 64;
        for (int s = t; s < 2048; s += 256) {
            int ci = s >> 6, w = s & 63;
            xt[ci][r][w + 1] = ok ? xrow[ci * 4096 + w] : 0.f;
        }
    }
    for (int s = t; s < 96; s += 256) {
        int ci = s / 3, r = s - ci * 3;
        xt[ci][r][0] = 0.f; xt[ci][r][65] = 0.f; xt[ci][r][66] = 0.f; xt[ci][r][67] = 0.f;
    }
    __syncthreads();
    int coq = t & 15, wq = t >> 4;
    float acc[4][4];
#pragma unroll
    for (int c = 0; c < 4; c++)
#pragma unroll
        for (int j = 0; j < 4; j++) acc[c][j] = 0.f;

    const float* wbase = wt + (size_t)ci0 * 9 * 64 + coq * 4;   // + (ci*9+q)*64
    for (int ci = 0; ci < 32; ci++) {
        float4 wv[9];
#pragma unroll
        for (int q = 0; q < 9; q++) wv[q] = *(const float4*)&wbase[(ci * 9 + q) * 64];
#pragma unroll
        for (int r = 0; r < 3; r++) {
            const float* row = &xt[ci][r][wq * 4];
            float4 f0 = ((const float4*)row)[0], f1 = ((const float4*)row)[1];
            float xr[8] = {f0.x, f0.y, f0.z, f0.w, f1.x, f1.y, f1.z, f1.w};
            float4 wa = wv[r * 3 + 0], wb = wv[r * 3 + 1], wc = wv[r * 3 + 2];
#pragma unroll
            for (int j = 0; j < 4; j++) {
                acc[0][j] += wa.x * xr[j] + wb.x * xr[j + 1] + wc.x * xr[j + 2];
                acc[1][j] += wa.y * xr[j] + wb.y * xr[j + 1] + wc.y * xr[j + 2];
                acc[2][j] += wa.z * xr[j] + wb.z * xr[j + 1] + wc.z * xr[j + 2];
                acc[3][j] += wa.w * xr[j] + wb.w * xr[j + 1] + wc.w * xr[j + 2];
            }
        }
    }
    float* dst = half ? out1 : out0;
#pragma unroll
    for (int cc = 0; cc < 4; cc++) {
        int co = coq * 4 + cc;
        float bias = half ? 0.f : cb[co];    // bias folded into half 0
        float4 o;
        o.x = acc[cc][0] + bias; o.y = acc[cc][1] + bias;
        o.z = acc[cc][2] + bias; o.w = acc[cc][3] + bias;
        *(float4*)&dst[((b * 64 + co) * 64 + h) * 64 + wq * 4] = o;
    }
}

// ---------------- GN stats over summed halves: 512 blocks, 1 channel each ----------------
__global__ __launch_bounds__(256) void k_gnstats2(const float* c0, const float* c1, float* gstats) {
    int bx = blockIdx.x;                  // (b*2+g)*32 + slice
    int slice = bx & 31; int bg = bx >> 5; int g = bg & 1; int b = bg >> 1;
    int t = threadIdx.x;
    size_t base = ((size_t)(b * 64 + g * 32 + slice)) * 4096;
    const float4* p0 = (const float4*)(c0 + base);
    const float4* p1 = (const float4*)(c1 + base);
    float s = 0.f, s2 = 0.f;
#pragma unroll
    for (int i = 0; i < 4; i++) {
        float4 a = p0[t + i * 256], bv = p1[t + i * 256];
        float vx = a.x + bv.x, vy = a.y + bv.y, vz = a.z + bv.z, vw = a.w + bv.w;
        s += vx + vy + vz + vw;
        s2 += vx * vx + vy * vy + vz * vz + vw * vw;
    }
#pragma unroll
    for (int off = 32; off; off >>= 1) { s += __shfl_xor(s, off); s2 += __shfl_xor(s2, off); }
    __shared__ float rs[4], rq[4];
    int wid = t >> 6;
    if ((t & 63) == 0) { rs[wid] = s; rq[wid] = s2; }
    __syncthreads();
    if (t == 0) {
        atomicAdd(&gstats[b * 4 + g * 2 + 0], rs[0] + rs[1] + rs[2] + rs[3]);
        atomicAdd(&gstats[b * 4 + g * 2 + 1], rq[0] + rq[1] + rq[2] + rq[3]);
    }
}

// ---------------- GN apply + SiLU + NCHW->NHWC -> y_nhwc (B,L,64) f32 ----------------
__global__ __launch_bounds__(256) void k_gnapply(const float* c0, const float* c1, const float* gstats,
                                                 fp gng, fp gnb, float* y_nhwc) {
    __shared__ float tile[64][65];
    int bx = blockIdx.x; int b = bx >> 6; int p0 = (bx & 63) * 64;
    int t = threadIdx.x;
    const float invN = 1.f / (32.f * 4096.f);
    float s0 = gstats[b * 4 + 0], q0 = gstats[b * 4 + 1];
    float s1 = gstats[b * 4 + 2], q1 = gstats[b * 4 + 3];
    float m0 = s0 * invN, r0 = rsqrtf(q0 * invN - m0 * m0 + 1e-5f);
    float m1 = s1 * invN, r1 = rsqrtf(q1 * invN - m1 * m1 + 1e-5f);
    for (int idx = t; idx < 4096; idx += 256) {
        int c = idx >> 6, pi = idx & 63;
        size_t gi = (size_t)(b * 64 + c) * LD + p0 + pi;
        float v = c0[gi] + c1[gi];
        float mean = (c < 32) ? m0 : m1, rstd = (c < 32) ? r0 : r1;
        v = (v - mean) * rstd * gng[c] + gnb[c];
        v = v * sigm(v);
        tile[c][pi] = v;
    }
    __syncthreads();
    for (int idx = t; idx < 4096; idx += 256) {
        int pi = idx >> 6, c = idx & 63;
        y_nhwc[(b * LD + p0 + pi) * 64 + c] = tile[c][pi];
    }
}

// ---------------- LayerNorm(64) + in_proj (64->256), 4 pixels/block -> xmc, zsil ----------------
__global__ __launch_bounds__(256) void k_lninproj(const float* y_nhwc, fp lng, fp lnb, fp ipw,
                                                  float* xmc, float* zsil) {
    __shared__ float hn[4][64];
    int bp0 = blockIdx.x * 4;            // 4 pixels
    int t = threadIdx.x;
    int pix = t >> 6, lane = t & 63;     // one wave per pixel
    {
        float v = y_nhwc[(bp0 + pix) * 64 + lane];
        float s = v, s2 = v * v;
#pragma unroll
        for (int off = 32; off; off >>= 1) { s += __shfl_xor(s, off); s2 += __shfl_xor(s2, off); }
        float mean = s * (1.f / 64.f);
        float rstd = rsqrtf(s2 * (1.f / 64.f) - mean * mean + 1e-5f);
        hn[pix][lane] = (v - mean) * rstd * lng[lane] + lnb[lane];
    }
    __syncthreads();
    float a0 = 0.f, a1 = 0.f, a2 = 0.f, a3 = 0.f;
    for (int c = 0; c < 64; c++) {
        float w = ipw[c * 256 + t];
        a0 += hn[0][c] * w; a1 += hn[1][c] * w; a2 += hn[2][c] * w; a3 += hn[3][c] * w;
    }
    float accv[4] = {a0, a1, a2, a3};
#pragma unroll
    for (int p = 0; p < 4; p++) {
        int bp = bp0 + p;
        float v = accv[p];
        if (t < 128) xmc[bp * 128 + t] = v;
        else         zsil[bp * 128 + (t - 128)] = v * sigm(v);
    }
}

// ---------------- depthwise conv3x3 + bias + SiLU -> xm_dw (B,L,128) f32 ----------------
__global__ __launch_bounds__(256) void k_dwconv(const float* xmc, fp dww, fp dwb, float* xm_dw) {
    int id = blockIdx.x * 256 + threadIdx.x;   // (b*L + p)*128 + d
    int d = id & 127, p = (id >> 7) & (LD - 1), b = id >> 19;
    int h = p >> 6, w = p & 63;
    float wv[9];
#pragma unroll
    for (int q = 0; q < 9; q++) wv[q] = dww[d * 9 + q];
    float acc = dwb[d];
#pragma unroll
    for (int i = 0; i < 3; i++) {
        int hs = h + i - 1; if (hs < 0 || hs > 63) continue;
#pragma unroll
        for (int j = 0; j < 3; j++) {
            int ws = w + j - 1; if (ws < 0 || ws > 63) continue;
            acc += xmc[((b << 12) + (hs << 6) + ws) * 128 + d] * wv[i * 3 + j];
        }
    }
    acc = acc * sigm(acc);
    xm_dw[id] = acc;
}

// ---------------- x_proj, direction-paired: one staged tile serves k and k+2 ----------------
__global__ __launch_bounds__(384) void k_proj(const float* xm_dw, fp xpw, float* dts4, float* xBC) {
    __shared__ float u_lds[128 * 65];    // [d][l], stride 65 (conflict-free)
    int bx = blockIdx.x;
    int lt = bx & 63; int bkp = bx >> 6; int kp = bkp & 1; int b = bkp >> 1;
    int l0 = lt * 64;
    int t = threadIdx.x;
    for (int idx = t; idx < 64 * 128; idx += 384) {
        int l = idx >> 7, d = idx & 127;
        u_lds[d * 65 + l] = xm_dw[(b * LD + pmap(kp, l0 + l)) * 128 + d];
    }
    __syncthreads();
    int l = t & 63;
    int w = t >> 6;                                          // 0..5, wave index
    int cgu  = __builtin_amdgcn_readfirstlane(w >> 1);       // 0..2 c-group
    int rev  = __builtin_amdgcn_readfirstlane(w & 1);        // 0: k=kp, 1: k=kp+2
    int ksel = rev ? (kp + 2) : kp;
    const float* wg = xpw + (size_t)(ksel * 36 + cgu * 12) * 128;   // uniform -> s_load
    float acc[12];
#pragma unroll
    for (int i = 0; i < 12; i++) acc[i] = 0.f;
    for (int d = 0; d < 128; d += 4) {
        float u0 = u_lds[(d + 0) * 65 + l];
        float u1 = u_lds[(d + 1) * 65 + l];
        float u2 = u_lds[(d + 2) * 65 + l];
        float u3 = u_lds[(d + 3) * 65 + l];
#pragma unroll
        for (int i = 0; i < 12; i++) {
            float4 wv = *(const float4*)&wg[i * 128 + d];
            acc[i] += wv.x * u0 + wv.y * u1 + wv.z * u2 + wv.w * u3;
        }
    }
    int pos = rev ? (LD - 1 - l0 - l) : (l0 + l);
    int base = (b * 4 + ksel) * LD + pos;
#pragma unroll
    for (int i = 0; i < 12; i++) {
        int c = cgu * 12 + i;
        if (c < 4) dts4[base * 4 + c] = acc[i];
        else       xBC[base * 32 + (c - 4)] = acc[i];
    }
}

// ---------------- scan phase 1: no LDS — dv/B via uniform scalar loads (constant cache) --------
__global__ __launch_bounds__(128) void k_scan1(const float* xm_dw, const float* dts4, const float* xBC,
                                               fp dtw, fp dtbp, fp alog,
                                               float* Pbuf, float* Hbuf, int NCr, int CLr) {
    int c = blockIdx.x, k = blockIdx.y, b = blockIdx.z;
    int d = threadIdx.x;
    int bk = b * 4 + k;
    int kd = k * 128 + d;
    float w0 = dtw[kd * 4 + 0], w1 = dtw[kd * 4 + 1], w2 = dtw[kd * 4 + 2], w3 = dtw[kd * 4 + 3];
    float dtb = dtbp[kd];
    float base = -__expf(alog[kd * 16]) * L2E;
    float A2[16];
    bool geo = true;
#pragma unroll
    for (int n = 0; n < 16; n++) {
        A2[n] = -__expf(alog[kd * 16 + n]) * L2E;
        float ideal = (float)(n + 1) * base;
        geo = geo && (fabsf(A2[n] - ideal) <= 1e-4f * fabsf(ideal));
    }
    float h[16]; float sdt = 0.f;
#pragma unroll
    for (int n = 0; n < 16; n++) h[n] = 0.f;
    int l0 = c * CLr;
    for (int ss = 0; ss < CLr; ss += 64) {
        int ls = l0 + ss;
        int row = __builtin_amdgcn_readfirstlane(bk * LD + ls);   // uniform
        const float4* drow = (const float4*)(dts4 + (size_t)row * 4);
        const float4* xrow = (const float4*)(xBC + (size_t)row * 32);
        int pbase = pmap(k, ls);
        int pstep = pmap(k, ls + 1) - pbase;     // exactly linear within 64-aligned tile
        const float* up = xm_dw + (size_t)(b * LD + pbase) * 128 + d;
        long ustep = (long)pstep * 128;
        if (geo) {
#pragma unroll 2
            for (int s = 0; s < 64; s++) {
                float4 dv = drow[s];                              // uniform -> s_load
                float dtv = softplusf(dv.x * w0 + dv.y * w1 + dv.z * w2 + dv.w * w3 + dtb);
                sdt += dtv;
                float u = *up; up += ustep;
                float du = dtv * u;
                float4 B0 = xrow[s * 8 + 0], B1 = xrow[s * 8 + 1];
                float4 B2 = xrow[s * 8 + 2], B3 = xrow[s * 8 + 3]; // uniform -> s_load
                float r = exp2f(dtv * base);
                float r2 = r * r, r3 = r2 * r, r4 = r2 * r2;
                float r5 = r4 * r, r6 = r4 * r2, r7 = r4 * r3, r8 = r4 * r4;
                float r9 = r8 * r, r10 = r8 * r2, r11 = r8 * r3, r12 = r8 * r4;
                float r13 = r8 * r5, r14 = r8 * r6, r15 = r8 * r7, r16 = r8 * r8;
                h[0]  = r   * h[0]  + du * B0.x;  h[1]  = r2  * h[1]  + du * B0.y;
                h[2]  = r3  * h[2]  + du * B0.z;  h[3]  = r4  * h[3]  + du * B0.w;
                h[4]  = r5  * h[4]  + du * B1.x;  h[5]  = r6  * h[5]  + du * B1.y;
                h[6]  = r7  * h[6]  + du * B1.z;  h[7]  = r8  * h[7]  + du * B1.w;
                h[8]  = r9  * h[8]  + du * B2.x;  h[9]  = r10 * h[9]  + du * B2.y;
                h[10] = r11 * h[10] + du * B2.z;  h[11] = r12 * h[11] + du * B2.w;
                h[12] = r13 * h[12] + du * B3.x;  h[13] = r14 * h[13] + du * B3.y;
                h[14] = r15 * h[14] + du * B3.z;  h[15] = r16 * h[15] + du * B3.w;
            }
        } else {
#pragma unroll 2
            for (int s = 0; s < 64; s++) {
                float4 dv = drow[s];
                float dtv = softplusf(dv.x * w0 + dv.y * w1 + dv.z * w2 + dv.w * w3 + dtb);
                sdt += dtv;
                float u = *up; up += ustep;
                float du = dtv * u;
                float Bv[16];
#pragma unroll
                for (int q = 0; q < 4; q++) {
                    float4 Bq = xrow[s * 8 + q];
                    Bv[4 * q] = Bq.x; Bv[4 * q + 1] = Bq.y; Bv[4 * q + 2] = Bq.z; Bv[4 * q + 3] = Bq.w;
                }
#pragma unroll
                for (int n = 0; n < 16; n++) {
                    float a = exp2f(dtv * A2[n]);
                    h[n] = a * h[n] + du * Bv[n];
                }
            }
        }
    }
    int obase = (bk * NCr + c) * 2048 + d;
#pragma unroll
    for (int n = 0; n < 16; n++) {
        Pbuf[obase + n * 128] = exp2f(sdt * A2[n]);
        Hbuf[obase + n * 128] = h[n];
    }
}

// ---------------- scan phase 2: chunk-boundary combine -> Hinit ----------------
__global__ __launch_bounds__(256) void k_scan2(const float* Pbuf, const float* Hbuf, float* Hinit, int NCr) {
    int id = blockIdx.x * 256 + threadIdx.x;
    int nd = id & 2047; int bk = id >> 11;
    float h = 0.f;
    int base = bk * NCr * 2048 + nd;
    for (int c = 0; c < NCr; c++) {
        int idx = base + c * 2048;
        Hinit[idx] = h;
        h = Hbuf[idx] + Pbuf[idx] * h;
    }
}

// ---------------- scan phase 3: no LDS — dv/B/C via uniform scalar loads ----------------
__global__ __launch_bounds__(128) void k_scan3(const float* xm_dw, const float* dts4, const float* xBC,
                                               fp dtw, fp dtbp, fp alog, fp dsp,
                                               const float* Hinit,
                                               float* yv0, float* yv1, float* yv2, float* yv3,
                                               int multi, int NCr, int CLr) {
    int c = blockIdx.x, k = blockIdx.y, b = blockIdx.z;
    int d = threadIdx.x;
    int bk = b * 4 + k;
    int kd = k * 128 + d;
    float* yvb = multi ? ((k == 0) ? yv0 : (k == 1) ? yv1 : (k == 2) ? yv2 : yv3) : yv0;
    float w0 = dtw[kd * 4 + 0], w1 = dtw[kd * 4 + 1], w2 = dtw[kd * 4 + 2], w3 = dtw[kd * 4 + 3];
    float dtb = dtbp[kd];
    float Dv = dsp[kd];
    float base = -__expf(alog[kd * 16]) * L2E;
    float A2[16];
    bool geo = true;
#pragma unroll
    for (int n = 0; n < 16; n++) {
        A2[n] = -__expf(alog[kd * 16 + n]) * L2E;
        float ideal = (float)(n + 1) * base;
        geo = geo && (fabsf(A2[n] - ideal) <= 1e-4f * fabsf(ideal));
    }
    int hbase = (bk * NCr + c) * 2048 + d;
    float h[16];
#pragma unroll
    for (int n = 0; n < 16; n++) h[n] = Hinit[hbase + n * 128];
    int l0 = c * CLr;
    for (int ss = 0; ss < CLr; ss += 64) {
        int ls = l0 + ss;
        int row = __builtin_amdgcn_readfirstlane(bk * LD + ls);   // uniform
        const float4* drow = (const float4*)(dts4 + (size_t)row * 4);
        const float4* xrow = (const float4*)(xBC + (size_t)row * 32);
        int pbase = pmap(k, ls);
        int pstep = pmap(k, ls + 1) - pbase;
        const float* up = xm_dw + (size_t)(b * LD + pbase) * 128 + d;
        float* yp = yvb + (size_t)(b * LD + pbase) * 128 + d;
        long ustep = (long)pstep * 128;
        if (geo) {
#pragma unroll 2
            for (int s = 0; s < 64; s++) {
                float4 dv = drow[s];                              // uniform -> s_load
                float dtv = softplusf(dv.x * w0 + dv.y * w1 + dv.z * w2 + dv.w * w3 + dtb);
                float u = *up; up += ustep;
                float du = dtv * u;
                float4 B0 = xrow[s * 8 + 0], B1 = xrow[s * 8 + 1];
                float4 B2 = xrow[s * 8 + 2], B3 = xrow[s * 8 + 3];
                float4 C0 = xrow[s * 8 + 4], C1 = xrow[s * 8 + 5];
                float4 C2 = xrow[s * 8 + 6], C3 = xrow[s * 8 + 7];
                float r = exp2f(dtv * base);
                float r2 = r * r, r3 = r2 * r, r4 = r2 * r2;
                float r5 = r4 * r, r6 = r4 * r2, r7 = r4 * r3, r8 = r4 * r4;
                float r9 = r8 * r, r10 = r8 * r2, r11 = r8 * r3, r12 = r8 * r4;
                float r13 = r8 * r5, r14 = r8 * r6, r15 = r8 * r7, r16 = r8 * r8;
                float y;
                h[0]  = r   * h[0]  + du * B0.x;  y  = h[0]  * C0.x;
                h[1]  = r2  * h[1]  + du * B0.y;  y += h[1]  * C0.y;
                h[2]  = r3  * h[2]  + du * B0.z;  y += h[2]  * C0.z;
                h[3]  = r4  * h[3]  + du * B0.w;  y += h[3]  * C0.w;
                h[4]  = r5  * h[4]  + du * B1.x;  y += h[4]  * C1.x;
                h[5]  = r6  * h[5]  + du * B1.y;  y += h[5]  * C1.y;
                h[6]  = r7  * h[6]  + du * B1.z;  y += h[6]  * C1.z;
                h[7]  = r8  * h[7]  + du * B1.w;  y += h[7]  * C1.w;
                h[8]  = r9  * h[8]  + du * B2.x;  y += h[8]  * C2.x;
                h[9]  = r10 * h[9]  + du * B2.y;  y += h[9]  * C2.y;
                h[10] = r11 * h[10] + du * B2.z;  y += h[10] * C2.z;
                h[11] = r12 * h[11] + du * B2.w;  y += h[11] * C2.w;
                h[12] = r13 * h[12] + du * B3.x;  y += h[12] * C3.x;
                h[13] = r14 * h[13] + du * B3.y;  y += h[13] * C3.y;
                h[14] = r15 * h[14] + du * B3.z;  y += h[14] * C3.z;
                h[15] = r16 * h[15] + du * B3.w;  y += h[15] * C3.w;
                y += Dv * u;
                if (multi) { *yp = y; } else { atomicAdd(yp, y); }
                yp += ustep;
            }
        } else {
#pragma unroll 2
            for (int s = 0; s < 64; s++) {
                float4 dv = drow[s];
                float dtv = softplusf(dv.x * w0 + dv.y * w1 + dv.z * w2 + dv.w * w3 + dtb);
                float u = *up; up += ustep;
                float du = dtv * u;
                float Bv[16], Cv[16];
#pragma unroll
                for (int q = 0; q < 4; q++) {
                    float4 Bq = xrow[s * 8 + q];
                    float4 Cq = xrow[s * 8 + 4 + q];
                    Bv[4 * q] = Bq.x; Bv[4 * q + 1] = Bq.y; Bv[4 * q + 2] = Bq.z; Bv[4 * q + 3] = Bq.w;
                    Cv[4 * q] = Cq.x; Cv[4 * q + 1] = Cq.y; Cv[4 * q + 2] = Cq.z; Cv[4 * q + 3] = Cq.w;
                }
                float y = 0.f;
#pragma unroll
                for (int n = 0; n < 16; n++) {
                    float a = exp2f(dtv * A2[n]);
                    h[n] = a * h[n] + du * Bv[n];
                    y += h[n] * Cv[n];
                }
                y += Dv * u;
                if (multi) { *yp = y; } else { atomicAdd(yp, y); }
                yp += ustep;
            }
        }
    }
}

// ---------------- final: sum 4 direction partials + LN(128) + gate + out_proj + residuals ----------------
__global__ __launch_bounds__(256) void k_final(const float* yv0, const float* yv1,
                                               const float* yv2, const float* yv3, int multi,
                                               const float* zsil, const float* y_nhwc,
                                               fp ong, fp onb, fp opw, float* out) {
    __shared__ float ylds[2][128];
    __shared__ float red[2][2][2];
    __shared__ float part[2][2][64];
    int bp0 = blockIdx.x * 2;
    int t = threadIdx.x;
    int pix = t >> 7, tl = t & 127;
    int bp = bp0 + pix;
    size_t gi = (size_t)bp * 128 + tl;
    float v = yv0[gi];
    if (multi) v += yv1[gi] + yv2[gi] + yv3[gi];
    float s = v, s2 = v * v;
#pragma unroll
    for (int off = 32; off; off >>= 1) { s += __shfl_xor(s, off); s2 += __shfl_xor(s2, off); }
    int wh = (t >> 6) & 1;
    if ((t & 63) == 0) { red[pix][wh][0] = s; red[pix][wh][1] = s2; }
    __syncthreads();
    float S = red[pix][0][0] + red[pix][1][0], S2 = red[pix][0][1] + red[pix][1][1];
    float mean = S * (1.f / 128.f);
    float rstd = rsqrtf(S2 * (1.f / 128.f) - mean * mean + 1e-5f);
    float vn = (v - mean) * rstd * ong[tl] + onb[tl];
    vn *= zsil[gi];
    ylds[pix][tl] = vn;
    __syncthreads();
    {   // matvec: 2 px × 2 halves × 64 co
        int px = t >> 7, half = (t >> 6) & 1, co = t & 63;
        float acc = 0.f;
        const float* yrow = &ylds[px][half * 64];
        const float* wcol = &opw[half * 64 * 64 + co];
#pragma unroll 16
        for (int dd = 0; dd < 64; dd++) acc += yrow[dd] * wcol[dd * 64];
        part[px][half][co] = acc;
    }
    __syncthreads();
    if (t < 128) {
        int pp = t >> 6, co = t & 63;
        int bpo = bp0 + pp;
        float a = part[pp][0][co] + part[pp][1][co];
        float yb = y_nhwc[bpo * 64 + co];
        out[((bpo >> 12) * 64 + co) * LD + (bpo & 4095)] = 2.f * yb + a;
    }
}

extern "C" void kernel_launch(void* const* d_in, const int* in_sizes, int n_in,
                              void* d_out, int out_size, void* d_ws, size_t ws_size,
                              hipStream_t stream) {
    fp x    = (fp)d_in[0];
    fp cw   = (fp)d_in[1];
    fp cb   = (fp)d_in[2];
    fp gng  = (fp)d_in[3];
    fp gnb  = (fp)d_in[4];
    fp lng  = (fp)d_in[5];
    fp lnb  = (fp)d_in[6];
    fp ipw  = (fp)d_in[7];
    fp dww  = (fp)d_in[8];
    fp dwb  = (fp)d_in[9];
    fp xpw  = (fp)d_in[10];
    fp dtw  = (fp)d_in[11];
    fp dtb  = (fp)d_in[12];
    fp alog = (fp)d_in[13];
    fp dsp  = (fp)d_in[14];
    fp ong  = (fp)d_in[15];
    fp onb  = (fp)d_in[16];
    fp opw  = (fp)d_in[17];

    // workspace layout (floats)
    float* w = (float*)d_ws;
    float* conv_out0 = w;  w += BD * 64 * LD;         // 2.10M floats (dead after gnapply)
    float* conv_out1 = w;  w += BD * 64 * LD;         // 2.10M (dead after gnapply) — contiguous with out0
    float* y_nhwc    = w;  w += BD * LD * 64;         // 2.10M
    float* gstats    = w;  w += 32;
    float* wt        = w;  w += 64 * 64 * 9;
    float* xmc       = w;  w += BD * LD * 128;        // 4.19M (dead after dwconv)
    float* zsil      = w;  w += BD * LD * 128;        // 4.19M
    float* xm_dw     = w;  w += BD * LD * 128;        // 4.19M
    float* dts4      = w;  w += BD * KDIR * LD * 4;   // 0.52M
    float* xBC       = w;  w += BD * KDIR * LD * 32;  // 4.19M
    float* yv        = w;  w += BD * LD * 128;        // 4.19M
    size_t base_floats = (size_t)(w - (float*)d_ws);

    // scan chunking + multi-buffer yv: prefer NC=64 + atomic-free scan3 if ws allows fresh P/H/Hinit
    int NCr = 32, multi = 0;
    size_t perbuf64 = (size_t)32 * 64 * 2048;         // 4.19M floats per buffer at NC=64
    float *Pbuf, *Hbuf, *Hinit, *yv1, *yv2, *yv3;
    if (ws_size >= (base_floats + 3 * perbuf64) * sizeof(float)) {
        NCr = 64; multi = 1;
        Pbuf  = w;  w += perbuf64;
        Hbuf  = w;  w += perbuf64;
        Hinit = w;  w += perbuf64;
        // direction-partial buffers alias dead regions (all 4.19M floats, safe by stream order):
        yv1 = Pbuf;        // dead after k_scan2
        yv2 = xmc;         // dead after k_dwconv
        yv3 = conv_out0;   // conv_out0+conv_out1 contiguous 4.19M, dead after k_gnapply
    } else {
        // aliased fallback: P/Hloc overlay xmc (dead), Hinit overlays conv_out0 (dead); atomic scan3
        Pbuf  = xmc;
        Hbuf  = xmc + (size_t)32 * 32 * 2048;
        Hinit = conv_out0;
        yv1 = yv2 = yv3 = yv;
    }
    int CLr = LD / NCr;
    if (ws_size < base_floats * sizeof(float)) return;

    hipMemsetAsync(gstats, 0, 32 * sizeof(float), stream);
    k_wt<<<144, 256, 0, stream>>>(cw, wt);
    k_conv<<<BD * HD * 2, 256, 0, stream>>>(x, wt, cb, conv_out0, conv_out1);
    k_gnstats2<<<BD * 2 * 32, 256, 0, stream>>>(conv_out0, conv_out1, gstats);
    k_gnapply<<<BD * 64, 256, 0, stream>>>(conv_out0, conv_out1, gstats, gng, gnb, y_nhwc);
    k_lninproj<<<BD * LD / 4, 256, 0, stream>>>(y_nhwc, lng, lnb, ipw, xmc, zsil);
    k_dwconv<<<BD * LD * 128 / 256, 256, 0, stream>>>(xmc, dww, dwb, xm_dw);
    k_proj<<<BD * 2 * 64, 384, 0, stream>>>(xm_dw, xpw, dts4, xBC);
    k_scan1<<<dim3(NCr, KDIR, BD), 128, 0, stream>>>(xm_dw, dts4, xBC, dtw, dtb, alog, Pbuf, Hbuf, NCr, CLr);
    k_scan2<<<256, 256, 0, stream>>>(Pbuf, Hbuf, Hinit, NCr);
    if (!multi) hipMemsetAsync(yv, 0, (size_t)BD * LD * 128 * sizeof(float), stream);
    k_scan3<<<dim3(NCr, KDIR, BD), 128, 0, stream>>>(xm_dw, dts4, xBC, dtw, dtb, alog, dsp, Hinit,
                                                     yv, yv1, yv2, yv3, multi, NCr, CLr);
    k_final<<<BD * LD / 2, 256, 0, stream>>>(yv, yv1, yv2, yv3, multi, zsil, y_nhwc, ong, onb, opw, (float*)d_out);
}

// Round 15
// 420.765 us; speedup vs baseline: 1.0761x; 1.0761x over previous
//
#include <hip/hip_runtime.h>
#include <hip/hip_bf16.h>

// Problem dims
#define BD   8
#define CD   64      // conv channels / COUT
#define HD   64
#define WD   64
#define LD   4096    // H*W
#define DINN 128
#define KDIR 4
#define NST  16      // d_state
#define L2E  1.442695040888963f

typedef const float* fp;
typedef float v2f __attribute__((ext_vector_type(2)));

__device__ __forceinline__ float sigm(float x) { return 1.f / (1.f + __expf(-x)); }
__device__ __forceinline__ float softplusf(float x) {
    float e = __expf(-fabsf(x));
    return fmaxf(x, 0.f) + __logf(1.f + e);
}
// scan position l -> pixel index, for direction k (read pixel == write pixel for all k)
__device__ __forceinline__ int pmap(int k, int l) {
    int m = (k & 2) ? (LD - 1 - l) : l;
    return (k & 1) ? (((m & 63) << 6) | (m >> 6)) : m;
}

// ---------------- weight transpose: cw [co][ci][3][3] -> wt [ci][q][co] ----------------
__global__ __launch_bounds__(256) void k_wt(fp cw, float* wt) {
    int id = blockIdx.x * 256 + threadIdx.x;
    if (id >= 64 * 64 * 9) return;
    int co = id & 63; int ciq = id >> 6; int ci = ciq / 9; int q = ciq % 9;
    wt[id] = cw[(co * 64 + ci) * 9 + q];
}

// ---------------- conv3x3 partial over 32 ci -> conv_out0/1 (B,64,H,W) f32 ----------------
__global__ __launch_bounds__(256, 4) void k_conv(fp x, const float* wt, fp cb,
                                                 float* out0, float* out1) {
    __shared__ float xt[32][3][68];   // [ci][row][w+1], padded
    int bx = blockIdx.x;
    int half = bx & 1; int bh = bx >> 1; int h = bh & 63; int b = bh >> 6;
    int t = threadIdx.x;
    int ci0 = half << 5;
#pragma unroll
    for (int r = 0; r < 3; r++) {
        int hs = h + r - 1;
        bool ok = (hs >= 0 && hs < 64);
        const float* xrow = x + (((size_t)b * 64 + ci0) * 64 + (ok ? hs : 0)) * 64;
        for (int s = t; s < 2048; s += 256) {
            int ci = s >> 6, w = s & 63;
            xt[ci][r][w + 1] = ok ? xrow[ci * 4096 + w] : 0.f;
        }
    }
    for (int s = t; s < 96; s += 256) {
        int ci = s / 3, r = s - ci * 3;
        xt[ci][r][0] = 0.f; xt[ci][r][65] = 0.f; xt[ci][r][66] = 0.f; xt[ci][r][67] = 0.f;
    }
    __syncthreads();
    int coq = t & 15, wq = t >> 4;
    float acc[4][4];
#pragma unroll
    for (int c = 0; c < 4; c++)
#pragma unroll
        for (int j = 0; j < 4; j++) acc[c][j] = 0.f;

    const float* wbase = wt + (size_t)ci0 * 9 * 64 + coq * 4;   // + (ci*9+q)*64
    for (int ci = 0; ci < 32; ci++) {
        float4 wv[9];
#pragma unroll
        for (int q = 0; q < 9; q++) wv[q] = *(const float4*)&wbase[(ci * 9 + q) * 64];
#pragma unroll
        for (int r = 0; r < 3; r++) {
            const float* row = &xt[ci][r][wq * 4];
            float4 f0 = ((const float4*)row)[0], f1 = ((const float4*)row)[1];
            float xr[8] = {f0.x, f0.y, f0.z, f0.w, f1.x, f1.y, f1.z, f1.w};
            float4 wa = wv[r * 3 + 0], wb = wv[r * 3 + 1], wc = wv[r * 3 + 2];
#pragma unroll
            for (int j = 0; j < 4; j++) {
                acc[0][j] += wa.x * xr[j] + wb.x * xr[j + 1] + wc.x * xr[j + 2];
                acc[1][j] += wa.y * xr[j] + wb.y * xr[j + 1] + wc.y * xr[j + 2];
                acc[2][j] += wa.z * xr[j] + wb.z * xr[j + 1] + wc.z * xr[j + 2];
                acc[3][j] += wa.w * xr[j] + wb.w * xr[j + 1] + wc.w * xr[j + 2];
            }
        }
    }
    float* dst = half ? out1 : out0;
#pragma unroll
    for (int cc = 0; cc < 4; cc++) {
        int co = coq * 4 + cc;
        float bias = half ? 0.f : cb[co];    // bias folded into half 0
        float4 o;
        o.x = acc[cc][0] + bias; o.y = acc[cc][1] + bias;
        o.z = acc[cc][2] + bias; o.w = acc[cc][3] + bias;
        *(float4*)&dst[((b * 64 + co) * 64 + h) * 64 + wq * 4] = o;
    }
}

// ---------------- GN stats over summed halves: 512 blocks, 1 channel each ----------------
__global__ __launch_bounds__(256) void k_gnstats2(const float* c0, const float* c1, float* gstats) {
    int bx = blockIdx.x;                  // (b*2+g)*32 + slice
    int slice = bx & 31; int bg = bx >> 5; int g = bg & 1; int b = bg >> 1;
    int t = threadIdx.x;
    size_t base = ((size_t)(b * 64 + g * 32 + slice)) * 4096;
    const float4* p0 = (const float4*)(c0 + base);
    const float4* p1 = (const float4*)(c1 + base);
    float s = 0.f, s2 = 0.f;
#pragma unroll
    for (int i = 0; i < 4; i++) {
        float4 a = p0[t + i * 256], bv = p1[t + i * 256];
        float vx = a.x + bv.x, vy = a.y + bv.y, vz = a.z + bv.z, vw = a.w + bv.w;
        s += vx + vy + vz + vw;
        s2 += vx * vx + vy * vy + vz * vz + vw * vw;
    }
#pragma unroll
    for (int off = 32; off; off >>= 1) { s += __shfl_xor(s, off); s2 += __shfl_xor(s2, off); }
    __shared__ float rs[4], rq[4];
    int wid = t >> 6;
    if ((t & 63) == 0) { rs[wid] = s; rq[wid] = s2; }
    __syncthreads();
    if (t == 0) {
        atomicAdd(&gstats[b * 4 + g * 2 + 0], rs[0] + rs[1] + rs[2] + rs[3]);
        atomicAdd(&gstats[b * 4 + g * 2 + 1], rq[0] + rq[1] + rq[2] + rq[3]);
    }
}

// ---------------- GN apply + SiLU + NCHW->NHWC -> y_nhwc (B,L,64) f32 ----------------
__global__ __launch_bounds__(256) void k_gnapply(const float* c0, const float* c1, const float* gstats,
                                                 fp gng, fp gnb, float* y_nhwc) {
    __shared__ float tile[64][65];
    int bx = blockIdx.x; int b = bx >> 6; int p0 = (bx & 63) * 64;
    int t = threadIdx.x;
    const float invN = 1.f / (32.f * 4096.f);
    float s0 = gstats[b * 4 + 0], q0 = gstats[b * 4 + 1];
    float s1 = gstats[b * 4 + 2], q1 = gstats[b * 4 + 3];
    float m0 = s0 * invN, r0 = rsqrtf(q0 * invN - m0 * m0 + 1e-5f);
    float m1 = s1 * invN, r1 = rsqrtf(q1 * invN - m1 * m1 + 1e-5f);
    for (int idx = t; idx < 4096; idx += 256) {
        int c = idx >> 6, pi = idx & 63;
        size_t gi = (size_t)(b * 64 + c) * LD + p0 + pi;
        float v = c0[gi] + c1[gi];
        float mean = (c < 32) ? m0 : m1, rstd = (c < 32) ? r0 : r1;
        v = (v - mean) * rstd * gng[c] + gnb[c];
        v = v * sigm(v);
        tile[c][pi] = v;
    }
    __syncthreads();
    for (int idx = t; idx < 4096; idx += 256) {
        int pi = idx >> 6, c = idx & 63;
        y_nhwc[(b * LD + p0 + pi) * 64 + c] = tile[c][pi];
    }
}

// ---------------- LayerNorm(64) + in_proj (64->256), 4 pixels/block -> xmc, zsil ----------------
__global__ __launch_bounds__(256) void k_lninproj(const float* y_nhwc, fp lng, fp lnb, fp ipw,
                                                  float* xmc, float* zsil) {
    __shared__ float hn[4][64];
    int bp0 = blockIdx.x * 4;            // 4 pixels
    int t = threadIdx.x;
    int pix = t >> 6, lane = t & 63;     // one wave per pixel
    {
        float v = y_nhwc[(bp0 + pix) * 64 + lane];
        float s = v, s2 = v * v;
#pragma unroll
        for (int off = 32; off; off >>= 1) { s += __shfl_xor(s, off); s2 += __shfl_xor(s2, off); }
        float mean = s * (1.f / 64.f);
        float rstd = rsqrtf(s2 * (1.f / 64.f) - mean * mean + 1e-5f);
        hn[pix][lane] = (v - mean) * rstd * lng[lane] + lnb[lane];
    }
    __syncthreads();
    float a0 = 0.f, a1 = 0.f, a2 = 0.f, a3 = 0.f;
    for (int c = 0; c < 64; c++) {
        float w = ipw[c * 256 + t];
        a0 += hn[0][c] * w; a1 += hn[1][c] * w; a2 += hn[2][c] * w; a3 += hn[3][c] * w;
    }
    float accv[4] = {a0, a1, a2, a3};
#pragma unroll
    for (int p = 0; p < 4; p++) {
        int bp = bp0 + p;
        float v = accv[p];
        if (t < 128) xmc[bp * 128 + t] = v;
        else         zsil[bp * 128 + (t - 128)] = v * sigm(v);
    }
}

// ---------------- depthwise conv3x3 + bias + SiLU -> xm_dw (B,L,128) f32 ----------------
__global__ __launch_bounds__(256) void k_dwconv(const float* xmc, fp dww, fp dwb, float* xm_dw) {
    int id = blockIdx.x * 256 + threadIdx.x;   // (b*L + p)*128 + d
    int d = id & 127, p = (id >> 7) & (LD - 1), b = id >> 19;
    int h = p >> 6, w = p & 63;
    float wv[9];
#pragma unroll
    for (int q = 0; q < 9; q++) wv[q] = dww[d * 9 + q];
    float acc = dwb[d];
#pragma unroll
    for (int i = 0; i < 3; i++) {
        int hs = h + i - 1; if (hs < 0 || hs > 63) continue;
#pragma unroll
        for (int j = 0; j < 3; j++) {
            int ws = w + j - 1; if (ws < 0 || ws > 63) continue;
            acc += xmc[((b << 12) + (hs << 6) + ws) * 128 + d] * wv[i * 3 + j];
        }
    }
    acc = acc * sigm(acc);
    xm_dw[id] = acc;
}

// ---------------- x_proj, direction-paired: one staged tile serves k and k+2 ----------------
__global__ __launch_bounds__(384) void k_proj(const float* xm_dw, fp xpw, float* dts4, float* xBC) {
    __shared__ float u_lds[128 * 65];    // [d][l], stride 65 (conflict-free)
    int bx = blockIdx.x;
    int lt = bx & 63; int bkp = bx >> 6; int kp = bkp & 1; int b = bkp >> 1;
    int l0 = lt * 64;
    int t = threadIdx.x;
    for (int idx = t; idx < 64 * 128; idx += 384) {
        int l = idx >> 7, d = idx & 127;
        u_lds[d * 65 + l] = xm_dw[(b * LD + pmap(kp, l0 + l)) * 128 + d];
    }
    __syncthreads();
    int l = t & 63;
    int w = t >> 6;                                          // 0..5, wave index
    int cgu  = __builtin_amdgcn_readfirstlane(w >> 1);       // 0..2 c-group
    int rev  = __builtin_amdgcn_readfirstlane(w & 1);        // 0: k=kp, 1: k=kp+2
    int ksel = rev ? (kp + 2) : kp;
    const float* wg = xpw + (size_t)(ksel * 36 + cgu * 12) * 128;   // uniform -> s_load
    float acc[12];
#pragma unroll
    for (int i = 0; i < 12; i++) acc[i] = 0.f;
    for (int d = 0; d < 128; d += 4) {
        float u0 = u_lds[(d + 0) * 65 + l];
        float u1 = u_lds[(d + 1) * 65 + l];
        float u2 = u_lds[(d + 2) * 65 + l];
        float u3 = u_lds[(d + 3) * 65 + l];
#pragma unroll
        for (int i = 0; i < 12; i++) {
            float4 wv = *(const float4*)&wg[i * 128 + d];
            acc[i] += wv.x * u0 + wv.y * u1 + wv.z * u2 + wv.w * u3;
        }
    }
    int pos = rev ? (LD - 1 - l0 - l) : (l0 + l);
    int base = (b * 4 + ksel) * LD + pos;
#pragma unroll
    for (int i = 0; i < 12; i++) {
        int c = cgu * 12 + i;
        if (c < 4) dts4[base * 4 + c] = acc[i];
        else       xBC[base * 32 + (c - 4)] = acc[i];
    }
}

// ---------------- scan phase 1: LDS-staged, packed v2f state math ----------------
__global__ __launch_bounds__(128) void k_scan1(const float* xm_dw, const float* dts4, const float* xBC,
                                               fp dtw, fp dtbp, fp alog,
                                               float* Pbuf, float* Hbuf, int NCr, int CLr) {
    __shared__ float s_b[64 * 16];
    __shared__ float s_d4[64 * 4];
    int c = blockIdx.x, k = blockIdx.y, b = blockIdx.z;
    int d = threadIdx.x;
    int bk = b * 4 + k;
    int kd = k * 128 + d;
    float w0 = dtw[kd * 4 + 0], w1 = dtw[kd * 4 + 1], w2 = dtw[kd * 4 + 2], w3 = dtw[kd * 4 + 3];
    float dtb = dtbp[kd];
    float base = -__expf(alog[kd * 16]) * L2E;
    float A2[16];
    bool geo = true;
#pragma unroll
    for (int n = 0; n < 16; n++) {
        A2[n] = -__expf(alog[kd * 16 + n]) * L2E;
        float ideal = (float)(n + 1) * base;
        geo = geo && (fabsf(A2[n] - ideal) <= 1e-4f * fabsf(ideal));
    }
    v2f h2[8]; float sdt = 0.f;
#pragma unroll
    for (int n = 0; n < 8; n++) h2[n] = (v2f){0.f, 0.f};
    int l0 = c * CLr;
    for (int ss = 0; ss < CLr; ss += 64) {
        if (ss) __syncthreads();
        int ls = l0 + ss;
        const float4* gd = (const float4*)&dts4[(size_t)(bk * LD + ls) * 4];
        if (d < 64) ((float4*)s_d4)[d] = gd[d];
        const float4* gx = (const float4*)&xBC[(size_t)(bk * LD + ls) * 32];
        for (int i = d; i < 64 * 4; i += 128) { int s = i >> 2, q = i & 3; ((float4*)s_b)[i] = gx[s * 8 + q]; }
        __syncthreads();
        int pbase = pmap(k, ls);
        int pstep = pmap(k, ls + 1) - pbase;     // exactly linear within 64-aligned tile
        const float* up = xm_dw + (size_t)(b * LD + pbase) * 128 + d;
        long ustep = (long)pstep * 128;
        if (geo) {
#pragma unroll 2
            for (int s = 0; s < 64; s++) {
                float4 dv = ((const float4*)s_d4)[s];
                float dtv = softplusf(dv.x * w0 + dv.y * w1 + dv.z * w2 + dv.w * w3 + dtb);
                sdt += dtv;
                float u = *up; up += ustep;
                float du = dtv * u;
                v2f du2 = {du, du};
                const float4* Bp = (const float4*)&s_b[s * 16];
                float4 B0 = Bp[0], B1 = Bp[1], B2 = Bp[2], B3 = Bp[3];
                float r = exp2f(dtv * base);
                float r2 = r * r;
                v2f sq = {r2, r2};
                v2f rp0 = {r, r2};
                v2f rp1 = rp0 * sq, rp2 = rp1 * sq, rp3 = rp2 * sq;
                v2f rp4 = rp3 * sq, rp5 = rp4 * sq, rp6 = rp5 * sq, rp7 = rp6 * sq;
                h2[0] = rp0 * h2[0] + du2 * (v2f){B0.x, B0.y};
                h2[1] = rp1 * h2[1] + du2 * (v2f){B0.z, B0.w};
                h2[2] = rp2 * h2[2] + du2 * (v2f){B1.x, B1.y};
                h2[3] = rp3 * h2[3] + du2 * (v2f){B1.z, B1.w};
                h2[4] = rp4 * h2[4] + du2 * (v2f){B2.x, B2.y};
                h2[5] = rp5 * h2[5] + du2 * (v2f){B2.z, B2.w};
                h2[6] = rp6 * h2[6] + du2 * (v2f){B3.x, B3.y};
                h2[7] = rp7 * h2[7] + du2 * (v2f){B3.z, B3.w};
            }
        } else {
#pragma unroll 2
            for (int s = 0; s < 64; s++) {
                float4 dv = ((const float4*)s_d4)[s];
                float dtv = softplusf(dv.x * w0 + dv.y * w1 + dv.z * w2 + dv.w * w3 + dtb);
                sdt += dtv;
                float u = *up; up += ustep;
                float du = dtv * u;
                const float* Bp = &s_b[s * 16];
#pragma unroll
                for (int n = 0; n < 8; n++) {
                    v2f a = {exp2f(dtv * A2[2 * n]), exp2f(dtv * A2[2 * n + 1])};
                    v2f Bv = {Bp[2 * n], Bp[2 * n + 1]};
                    h2[n] = a * h2[n] + (v2f){du, du} * Bv;
                }
            }
        }
    }
    int obase = (bk * NCr + c) * 2048 + d;
#pragma unroll
    for (int n = 0; n < 8; n++) {
        Pbuf[obase + (2 * n) * 128]     = exp2f(sdt * A2[2 * n]);
        Pbuf[obase + (2 * n + 1) * 128] = exp2f(sdt * A2[2 * n + 1]);
        Hbuf[obase + (2 * n) * 128]     = h2[n].x;
        Hbuf[obase + (2 * n + 1) * 128] = h2[n].y;
    }
}

// ---------------- scan phase 2: chunk-boundary combine -> Hinit ----------------
__global__ __launch_bounds__(256) void k_scan2(const float* Pbuf, const float* Hbuf, float* Hinit, int NCr) {
    int id = blockIdx.x * 256 + threadIdx.x;
    int nd = id & 2047; int bk = id >> 11;
    float h = 0.f;
    int base = bk * NCr * 2048 + nd;
    for (int c = 0; c < NCr; c++) {
        int idx = base + c * 2048;
        Hinit[idx] = h;
        h = Hbuf[idx] + Pbuf[idx] * h;
    }
}

// ---------------- scan phase 3: LDS-staged, packed v2f state math ----------------
__global__ __launch_bounds__(128) void k_scan3(const float* xm_dw, const float* dts4, const float* xBC,
                                               fp dtw, fp dtbp, fp alog, fp dsp,
                                               const float* Hinit,
                                               float* yv0, float* yv1, float* yv2, float* yv3,
                                               int multi, int NCr, int CLr) {
    __shared__ float s_bc[64 * 32];
    __shared__ float s_d4[64 * 4];
    int c = blockIdx.x, k = blockIdx.y, b = blockIdx.z;
    int d = threadIdx.x;
    int bk = b * 4 + k;
    int kd = k * 128 + d;
    float* yvb = multi ? ((k == 0) ? yv0 : (k == 1) ? yv1 : (k == 2) ? yv2 : yv3) : yv0;
    float w0 = dtw[kd * 4 + 0], w1 = dtw[kd * 4 + 1], w2 = dtw[kd * 4 + 2], w3 = dtw[kd * 4 + 3];
    float dtb = dtbp[kd];
    float Dv = dsp[kd];
    float base = -__expf(alog[kd * 16]) * L2E;
    float A2[16];
    bool geo = true;
#pragma unroll
    for (int n = 0; n < 16; n++) {
        A2[n] = -__expf(alog[kd * 16 + n]) * L2E;
        float ideal = (float)(n + 1) * base;
        geo = geo && (fabsf(A2[n] - ideal) <= 1e-4f * fabsf(ideal));
    }
    int hbase = (bk * NCr + c) * 2048 + d;
    v2f h2[8];
#pragma unroll
    for (int n = 0; n < 8; n++) {
        h2[n].x = Hinit[hbase + (2 * n) * 128];
        h2[n].y = Hinit[hbase + (2 * n + 1) * 128];
    }
    int l0 = c * CLr;
    for (int ss = 0; ss < CLr; ss += 64) {
        if (ss) __syncthreads();
        int ls = l0 + ss;
        const float4* gd = (const float4*)&dts4[(size_t)(bk * LD + ls) * 4];
        if (d < 64) ((float4*)s_d4)[d] = gd[d];
        const float4* gx = (const float4*)&xBC[(size_t)(bk * LD + ls) * 32];
        for (int i = d; i < 64 * 8; i += 128) ((float4*)s_bc)[i] = gx[i];
        __syncthreads();
        int pbase = pmap(k, ls);
        int pstep = pmap(k, ls + 1) - pbase;
        const float* up = xm_dw + (size_t)(b * LD + pbase) * 128 + d;
        float* yp = yvb + (size_t)(b * LD + pbase) * 128 + d;
        long ustep = (long)pstep * 128;
        if (geo) {
#pragma unroll 2
            for (int s = 0; s < 64; s++) {
                float4 dv = ((const float4*)s_d4)[s];
                float dtv = softplusf(dv.x * w0 + dv.y * w1 + dv.z * w2 + dv.w * w3 + dtb);
                float u = *up; up += ustep;
                float du = dtv * u;
                v2f du2 = {du, du};
                const float4* Bp = (const float4*)&s_bc[s * 32];
                float4 B0 = Bp[0], B1 = Bp[1], B2 = Bp[2], B3 = Bp[3];
                float4 C0 = Bp[4], C1 = Bp[5], C2 = Bp[6], C3 = Bp[7];
                float r = exp2f(dtv * base);
                float r2 = r * r;
                v2f sq = {r2, r2};
                v2f rp0 = {r, r2};
                v2f rp1 = rp0 * sq, rp2 = rp1 * sq, rp3 = rp2 * sq;
                v2f rp4 = rp3 * sq, rp5 = rp4 * sq, rp6 = rp5 * sq, rp7 = rp6 * sq;
                v2f y2;
                h2[0] = rp0 * h2[0] + du2 * (v2f){B0.x, B0.y};  y2  = h2[0] * (v2f){C0.x, C0.y};
                h2[1] = rp1 * h2[1] + du2 * (v2f){B0.z, B0.w};  y2 += h2[1] * (v2f){C0.z, C0.w};
                h2[2] = rp2 * h2[2] + du2 * (v2f){B1.x, B1.y};  y2 += h2[2] * (v2f){C1.x, C1.y};
                h2[3] = rp3 * h2[3] + du2 * (v2f){B1.z, B1.w};  y2 += h2[3] * (v2f){C1.z, C1.w};
                h2[4] = rp4 * h2[4] + du2 * (v2f){B2.x, B2.y};  y2 += h2[4] * (v2f){C2.x, C2.y};
                h2[5] = rp5 * h2[5] + du2 * (v2f){B2.z, B2.w};  y2 += h2[5] * (v2f){C2.z, C2.w};
                h2[6] = rp6 * h2[6] + du2 * (v2f){B3.x, B3.y};  y2 += h2[6] * (v2f){C3.x, C3.y};
                h2[7] = rp7 * h2[7] + du2 * (v2f){B3.z, B3.w};  y2 += h2[7] * (v2f){C3.z, C3.w};
                float y = y2.x + y2.y + Dv * u;
                if (multi) { *yp = y; } else { atomicAdd(yp, y); }
                yp += ustep;
            }
        } else {
#pragma unroll 2
            for (int s = 0; s < 64; s++) {
                float4 dv = ((const float4*)s_d4)[s];
                float dtv = softplusf(dv.x * w0 + dv.y * w1 + dv.z * w2 + dv.w * w3 + dtb);
                float u = *up; up += ustep;
                float du = dtv * u;
                const float* Bp = &s_bc[s * 32];
                v2f y2 = {0.f, 0.f};
#pragma unroll
                for (int n = 0; n < 8; n++) {
                    v2f a = {exp2f(dtv * A2[2 * n]), exp2f(dtv * A2[2 * n + 1])};
                    v2f Bv = {Bp[2 * n], Bp[2 * n + 1]};
                    v2f Cv = {Bp[16 + 2 * n], Bp[16 + 2 * n + 1]};
                    h2[n] = a * h2[n] + (v2f){du, du} * Bv;
                    y2 += h2[n] * Cv;
                }
                float y = y2.x + y2.y + Dv * u;
                if (multi) { *yp = y; } else { atomicAdd(yp, y); }
                yp += ustep;
            }
        }
    }
}

// ---------------- final: sum 4 direction partials + LN(128) + gate + out_proj + residuals ----------------
__global__ __launch_bounds__(256) void k_final(const float* yv0, const float* yv1,
                                               const float* yv2, const float* yv3, int multi,
                                               const float* zsil, const float* y_nhwc,
                                               fp ong, fp onb, fp opw, float* out) {
    __shared__ float ylds[2][128];
    __shared__ float red[2][2][2];
    __shared__ float part[2][2][64];
    int bp0 = blockIdx.x * 2;
    int t = threadIdx.x;
    int pix = t >> 7, tl = t & 127;
    int bp = bp0 + pix;
    size_t gi = (size_t)bp * 128 + tl;
    float v = yv0[gi];
    if (multi) v += yv1[gi] + yv2[gi] + yv3[gi];
    float s = v, s2 = v * v;
#pragma unroll
    for (int off = 32; off; off >>= 1) { s += __shfl_xor(s, off); s2 += __shfl_xor(s2, off); }
    int wh = (t >> 6) & 1;
    if ((t & 63) == 0) { red[pix][wh][0] = s; red[pix][wh][1] = s2; }
    __syncthreads();
    float S = red[pix][0][0] + red[pix][1][0], S2 = red[pix][0][1] + red[pix][1][1];
    float mean = S * (1.f / 128.f);
    float rstd = rsqrtf(S2 * (1.f / 128.f) - mean * mean + 1e-5f);
    float vn = (v - mean) * rstd * ong[tl] + onb[tl];
    vn *= zsil[gi];
    ylds[pix][tl] = vn;
    __syncthreads();
    {   // matvec: 2 px × 2 halves × 64 co
        int px = t >> 7, half = (t >> 6) & 1, co = t & 63;
        float acc = 0.f;
        const float* yrow = &ylds[px][half * 64];
        const float* wcol = &opw[half * 64 * 64 + co];
#pragma unroll 16
        for (int dd = 0; dd < 64; dd++) acc += yrow[dd] * wcol[dd * 64];
        part[px][half][co] = acc;
    }
    __syncthreads();
    if (t < 128) {
        int pp = t >> 6, co = t & 63;
        int bpo = bp0 + pp;
        float a = part[pp][0][co] + part[pp][1][co];
        float yb = y_nhwc[bpo * 64 + co];
        out[((bpo >> 12) * 64 + co) * LD + (bpo & 4095)] = 2.f * yb + a;
    }
}

extern "C" void kernel_launch(void* const* d_in, const int* in_sizes, int n_in,
                              void* d_out, int out_size, void* d_ws, size_t ws_size,
                              hipStream_t stream) {
    fp x    = (fp)d_in[0];
    fp cw   = (fp)d_in[1];
    fp cb   = (fp)d_in[2];
    fp gng  = (fp)d_in[3];
    fp gnb  = (fp)d_in[4];
    fp lng  = (fp)d_in[5];
    fp lnb  = (fp)d_in[6];
    fp ipw  = (fp)d_in[7];
    fp dww  = (fp)d_in[8];
    fp dwb  = (fp)d_in[9];
    fp xpw  = (fp)d_in[10];
    fp dtw  = (fp)d_in[11];
    fp dtb  = (fp)d_in[12];
    fp alog = (fp)d_in[13];
    fp dsp  = (fp)d_in[14];
    fp ong  = (fp)d_in[15];
    fp onb  = (fp)d_in[16];
    fp opw  = (fp)d_in[17];

    // workspace layout (floats)
    float* w = (float*)d_ws;
    float* conv_out0 = w;  w += BD * 64 * LD;         // 2.10M floats (dead after gnapply)
    float* conv_out1 = w;  w += BD * 64 * LD;         // 2.10M (dead after gnapply) — contiguous with out0
    float* y_nhwc    = w;  w += BD * LD * 64;         // 2.10M
    float* gstats    = w;  w += 32;
    float* wt        = w;  w += 64 * 64 * 9;
    float* xmc       = w;  w += BD * LD * 128;        // 4.19M (dead after dwconv)
    float* zsil      = w;  w += BD * LD * 128;        // 4.19M
    float* xm_dw     = w;  w += BD * LD * 128;        // 4.19M
    float* dts4      = w;  w += BD * KDIR * LD * 4;   // 0.52M
    float* xBC       = w;  w += BD * KDIR * LD * 32;  // 4.19M
    float* yv        = w;  w += BD * LD * 128;        // 4.19M
    size_t base_floats = (size_t)(w - (float*)d_ws);

    // scan chunking + multi-buffer yv: prefer NC=64 + atomic-free scan3 if ws allows fresh P/H/Hinit
    int NCr = 32, multi = 0;
    size_t perbuf64 = (size_t)32 * 64 * 2048;         // 4.19M floats per buffer at NC=64
    float *Pbuf, *Hbuf, *Hinit, *yv1, *yv2, *yv3;
    if (ws_size >= (base_floats + 3 * perbuf64) * sizeof(float)) {
        NCr = 64; multi = 1;
        Pbuf  = w;  w += perbuf64;
        Hbuf  = w;  w += perbuf64;
        Hinit = w;  w += perbuf64;
        // direction-partial buffers alias dead regions (all 4.19M floats, safe by stream order):
        yv1 = Pbuf;        // dead after k_scan2
        yv2 = xmc;         // dead after k_dwconv
        yv3 = conv_out0;   // conv_out0+conv_out1 contiguous 4.19M, dead after k_gnapply
    } else {
        // aliased fallback: P/Hloc overlay xmc (dead), Hinit overlays conv_out0 (dead); atomic scan3
        Pbuf  = xmc;
        Hbuf  = xmc + (size_t)32 * 32 * 2048;
        Hinit = conv_out0;
        yv1 = yv2 = yv3 = yv;
    }
    int CLr = LD / NCr;
    if (ws_size < base_floats * sizeof(float)) return;

    hipMemsetAsync(gstats, 0, 32 * sizeof(float), stream);
    k_wt<<<144, 256, 0, stream>>>(cw, wt);
    k_conv<<<BD * HD * 2, 256, 0, stream>>>(x, wt, cb, conv_out0, conv_out1);
    k_gnstats2<<<BD * 2 * 32, 256, 0, stream>>>(conv_out0, conv_out1, gstats);
    k_gnapply<<<BD * 64, 256, 0, stream>>>(conv_out0, conv_out1, gstats, gng, gnb, y_nhwc);
    k_lninproj<<<BD * LD / 4, 256, 0, stream>>>(y_nhwc, lng, lnb, ipw, xmc, zsil);
    k_dwconv<<<BD * LD * 128 / 256, 256, 0, stream>>>(xmc, dww, dwb, xm_dw);
    k_proj<<<BD * 2 * 64, 384, 0, stream>>>(xm_dw, xpw, dts4, xBC);
    k_scan1<<<dim3(NCr, KDIR, BD), 128, 0, stream>>>(xm_dw, dts4, xBC, dtw, dtb, alog, Pbuf, Hbuf, NCr, CLr);
    k_scan2<<<256, 256, 0, stream>>>(Pbuf, Hbuf, Hinit, NCr);
    if (!multi) hipMemsetAsync(yv, 0, (size_t)BD * LD * 128 * sizeof(float), stream);
    k_scan3<<<dim3(NCr, KDIR, BD), 128, 0, stream>>>(xm_dw, dts4, xBC, dtw, dtb, alog, dsp, Hinit,
                                                     yv, yv1, yv2, yv3, multi, NCr, CLr);
    k_final<<<BD * LD / 2, 256, 0, stream>>>(yv, yv1, yv2, yv3, multi, zsil, y_nhwc, ong, onb, opw, (float*)d_out);
}